// Round 2
// baseline (5418.391 us; speedup 1.0000x reference)
//
#include <hip/hip_runtime.h>
#include <math.h>

#define SEQ 2048
#define NH 8
#define DK 64
#define DM 512
#define RSCALE 0.125f

// ---------------- fp32 tiled GEMM: C = A(Mx512) @ W(512x512) ----------------
// mode 0: C[(((b*NH+h)*SEQ + s)*DK + d]          (b = m/SEQ, s = m%SEQ, h = n/DK, d = n%DK)
// mode 1: C[m*DM + n]                            (plain row-major)
// mode 2: C[(((b*NH+h)*DK + d)*SEQ + s]          (d-major / transposed per head)
// mode 3: 4 shifted copies of mode-2 (b==0):     C[rr*NH*DK*SEQ + (h*DK+d)*SEQ + (s-rr)], rr=0..3
__global__ __launch_bounds__(256)
void gemm512(const float* __restrict__ A, const float* __restrict__ W,
             float* __restrict__ C, int mode) {
  __shared__ float As[16][68];
  __shared__ float Ws[16][68];
  const int tid = threadIdx.x;
  const int m0 = blockIdx.x * 64, n0 = blockIdx.y * 64;
  const int tx = tid & 15, ty = tid >> 4;
  const int lm = tid >> 2, lkq = (tid & 3) * 4;
  const int lk = tid >> 4, lnq = (tid & 15) * 4;
  float acc[4][4] = {};
  for (int k0 = 0; k0 < DM; k0 += 16) {
    const float4 a = *(const float4*)(A + (size_t)(m0 + lm) * DM + k0 + lkq);
    const float4 w = *(const float4*)(W + (size_t)(k0 + lk) * DM + n0 + lnq);
    As[lkq + 0][lm] = a.x; As[lkq + 1][lm] = a.y;
    As[lkq + 2][lm] = a.z; As[lkq + 3][lm] = a.w;
    *(float4*)&Ws[lk][lnq] = w;
    __syncthreads();
#pragma unroll
    for (int k = 0; k < 16; ++k) {
      const float4 b4 = *(const float4*)&Ws[k][tx * 4];
      const float a0 = As[k][ty * 4 + 0], a1 = As[k][ty * 4 + 1];
      const float a2 = As[k][ty * 4 + 2], a3 = As[k][ty * 4 + 3];
      acc[0][0] += a0 * b4.x; acc[0][1] += a0 * b4.y; acc[0][2] += a0 * b4.z; acc[0][3] += a0 * b4.w;
      acc[1][0] += a1 * b4.x; acc[1][1] += a1 * b4.y; acc[1][2] += a1 * b4.z; acc[1][3] += a1 * b4.w;
      acc[2][0] += a2 * b4.x; acc[2][1] += a2 * b4.y; acc[2][2] += a2 * b4.z; acc[2][3] += a2 * b4.w;
      acc[3][0] += a3 * b4.x; acc[3][1] += a3 * b4.y; acc[3][2] += a3 * b4.z; acc[3][3] += a3 * b4.w;
    }
    __syncthreads();
  }
#pragma unroll
  for (int im = 0; im < 4; ++im) {
    const int m = m0 + ty * 4 + im;
    const int b = m >> 11, s = m & (SEQ - 1);
#pragma unroll
    for (int in = 0; in < 4; ++in) {
      const int n = n0 + tx * 4 + in;
      const int h = n >> 6, d = n & 63;
      const float v = acc[im][in];
      if (mode == 0) {
        C[(((size_t)b * NH + h) * SEQ + s) * DK + d] = v;
      } else if (mode == 1) {
        C[(size_t)m * DM + n] = v;
      } else if (mode == 2) {
        C[(((size_t)b * NH + h) * DK + d) * SEQ + s] = v;
      } else {
        const size_t rowb = ((size_t)h * DK + d) * SEQ;
#pragma unroll
        for (int rr = 0; rr < 4; ++rr) {
          const int t = s - rr;
          if (t >= 0) C[(size_t)rr * (NH * DK * SEQ) + rowb + t] = v;
        }
      }
    }
  }
}

// ---------------- fused relative attention (flash-style, fp32) ----------------
// Q: [bh][s][d], Kt: [bh][d][s], V: [bh][s][d], Ptc: 4 shifted copies of [h][d][s]
// scores(i,j) = ((Q[i]+u).K[j] + shift(i,j)) * RSCALE
// shift(i,j) = (Q[i]+v).P[j-i+S-1]  (j<=i);  0 (j==i+1);  (Q[i+1]+v).P[j-i-2]  (j>i+1)
__global__ __launch_bounds__(256)
void rel_attn(const float* __restrict__ Q, const float* __restrict__ Kt,
              const float* __restrict__ V, const float* __restrict__ Ptc,
              const float* __restrict__ ub, const float* __restrict__ vbias,
              float* __restrict__ ctx) {
  const int bh = blockIdx.y;
  const int b = bh >> 3, h = bh & 7;
  const int i0 = blockIdx.x * 16;
  const float* Qb  = Q  + (size_t)bh * (SEQ * DK);
  const float* KtB = Kt + (size_t)bh * (DK * SEQ);
  const float* Vb  = V  + (size_t)bh * (SEQ * DK);

  __shared__ float Qu[16][68];
  __shared__ float Qv[17][68];
  __shared__ float pb[16][68];

  const int tid = threadIdx.x;
  {
    const int rr = tid >> 4, d4 = (tid & 15) * 4;
    const float4 q  = *(const float4*)(Qb + (size_t)(i0 + rr) * DK + d4);
    const float4 uu = *(const float4*)(ub + h * DK + d4);
    const float4 vv = *(const float4*)(vbias + h * DK + d4);
    *(float4*)&Qu[rr][d4] = make_float4(q.x + uu.x, q.y + uu.y, q.z + uu.z, q.w + uu.w);
    *(float4*)&Qv[rr][d4] = make_float4(q.x + vv.x, q.y + vv.y, q.z + vv.z, q.w + vv.w);
    if (tid < 16) {
      const int d4b = tid * 4;
      const int row = i0 + 16;
      float4 q2 = make_float4(0.f, 0.f, 0.f, 0.f);
      if (row < SEQ) q2 = *(const float4*)(Qb + (size_t)row * DK + d4b);
      const float4 v2 = *(const float4*)(vbias + h * DK + d4b);
      *(float4*)&Qv[16][d4b] = make_float4(q2.x + v2.x, q2.y + v2.y, q2.z + v2.z, q2.w + v2.w);
    }
  }
  __syncthreads();

  const int lane = tid & 63;
  const int wv = tid >> 6;
  const int rh = lane >> 4, c4 = lane & 15;
  const int r = wv * 4 + rh;     // local row 0..15
  const int i = i0 + r;          // global query row

  float m_run = -INFINITY, l_run = 0.f;
  float acc0 = 0.f, acc1 = 0.f, acc2 = 0.f, acc3 = 0.f;

  for (int j0t = 0; j0t < SEQ; j0t += 64) {
    const int jmin = j0t + c4 * 4;
    float sc0 = 0.f, sc1 = 0.f, sc2 = 0.f, sc3 = 0.f;
    {  // content: (Q+u) . K
      const float* kp = KtB + jmin;
#pragma unroll 4
      for (int d4 = 0; d4 < DK; d4 += 4) {
        const float4 qu = *(const float4*)&Qu[r][d4];
        const float4 k0 = *(const float4*)(kp + (size_t)(d4 + 0) * SEQ);
        const float4 k1 = *(const float4*)(kp + (size_t)(d4 + 1) * SEQ);
        const float4 k2 = *(const float4*)(kp + (size_t)(d4 + 2) * SEQ);
        const float4 k3 = *(const float4*)(kp + (size_t)(d4 + 3) * SEQ);
        sc0 += qu.x * k0.x + qu.y * k1.x + qu.z * k2.x + qu.w * k3.x;
        sc1 += qu.x * k0.y + qu.y * k1.y + qu.z * k2.y + qu.w * k3.y;
        sc2 += qu.x * k0.z + qu.y * k1.z + qu.z * k2.z + qu.w * k3.z;
        sc3 += qu.x * k0.w + qu.y * k1.w + qu.z * k2.w + qu.w * k3.w;
      }
    }
    float p10 = 0.f, p11 = 0.f, p12 = 0.f, p13 = 0.f;
    if (jmin <= i) {               // pos region 1 (j <= i): (Q[i]+v) . P[j-i+S-1]
      const int off = jmin + (SEQ - 1) - i;   // always >= 0 here
      const int sh = off & 3;
      const float* pp = Ptc + (size_t)sh * (NH * DK * SEQ) + (size_t)h * (DK * SEQ) + (off - sh);
#pragma unroll 4
      for (int d4 = 0; d4 < DK; d4 += 4) {
        const float4 qv = *(const float4*)&Qv[r][d4];
        const float4 p0 = *(const float4*)(pp + (ptrdiff_t)(d4 + 0) * SEQ);
        const float4 p1 = *(const float4*)(pp + (ptrdiff_t)(d4 + 1) * SEQ);
        const float4 p2 = *(const float4*)(pp + (ptrdiff_t)(d4 + 2) * SEQ);
        const float4 p3 = *(const float4*)(pp + (ptrdiff_t)(d4 + 3) * SEQ);
        p10 += qv.x * p0.x + qv.y * p1.x + qv.z * p2.x + qv.w * p3.x;
        p11 += qv.x * p0.y + qv.y * p1.y + qv.z * p2.y + qv.w * p3.y;
        p12 += qv.x * p0.z + qv.y * p1.z + qv.z * p2.z + qv.w * p3.z;
        p13 += qv.x * p0.w + qv.y * p1.w + qv.z * p2.w + qv.w * p3.w;
      }
    }
    float p20 = 0.f, p21 = 0.f, p22 = 0.f, p23 = 0.f;
    if (jmin + 2 > i) {            // pos region 2 (j > i+1): (Q[i+1]+v) . P[j-i-2]
      const int off = jmin - i - 2;           // can be -3..-1 at the diagonal
      const int off_eff = off >= 0 ? off : 0; // clamp to an aligned, in-bounds base
      const int sh = off_eff & 3;
      const float* pp = Ptc + (size_t)sh * (NH * DK * SEQ) + (size_t)h * (DK * SEQ) + (off_eff - sh);
      float t0 = 0.f, t1 = 0.f, t2 = 0.f, t3 = 0.f;  // t_k = (Q[i+1]+v) . P[off_eff + k]
#pragma unroll 4
      for (int d4 = 0; d4 < DK; d4 += 4) {
        const float4 qv = *(const float4*)&Qv[r + 1][d4];
        const float4 p0 = *(const float4*)(pp + (ptrdiff_t)(d4 + 0) * SEQ);
        const float4 p1 = *(const float4*)(pp + (ptrdiff_t)(d4 + 1) * SEQ);
        const float4 p2 = *(const float4*)(pp + (ptrdiff_t)(d4 + 2) * SEQ);
        const float4 p3 = *(const float4*)(pp + (ptrdiff_t)(d4 + 3) * SEQ);
        t0 += qv.x * p0.x + qv.y * p1.x + qv.z * p2.x + qv.w * p3.x;
        t1 += qv.x * p0.y + qv.y * p1.y + qv.z * p2.y + qv.w * p3.y;
        t2 += qv.x * p0.z + qv.y * p1.z + qv.z * p2.z + qv.w * p3.z;
        t3 += qv.x * p0.w + qv.y * p1.w + qv.z * p2.w + qv.w * p3.w;
      }
      if (off >= 0) {
        p20 = t0; p21 = t1; p22 = t2; p23 = t3;
      } else if (off == -1) {
        p21 = t0; p22 = t1; p23 = t2;
      } else if (off == -2) {
        p22 = t0; p23 = t1;
      } else {  // off == -3
        p23 = t0;
      }
    }
    {
      const float pos0 = (jmin + 0 <= i) ? p10 : ((jmin + 0 == i + 1) ? 0.f : p20);
      const float pos1 = (jmin + 1 <= i) ? p11 : ((jmin + 1 == i + 1) ? 0.f : p21);
      const float pos2 = (jmin + 2 <= i) ? p12 : ((jmin + 2 == i + 1) ? 0.f : p22);
      const float pos3 = (jmin + 3 <= i) ? p13 : ((jmin + 3 == i + 1) ? 0.f : p23);
      sc0 = (sc0 + pos0) * RSCALE;
      sc1 = (sc1 + pos1) * RSCALE;
      sc2 = (sc2 + pos2) * RSCALE;
      sc3 = (sc3 + pos3) * RSCALE;
    }
    // online softmax over this 64-wide tile; each row lives in 16 lanes (same rh)
    float tmax = fmaxf(fmaxf(sc0, sc1), fmaxf(sc2, sc3));
#pragma unroll
    for (int m = 1; m <= 8; m <<= 1) tmax = fmaxf(tmax, __shfl_xor(tmax, m));
    const float mnew = fmaxf(m_run, tmax);
    const float e0 = __expf(sc0 - mnew), e1 = __expf(sc1 - mnew);
    const float e2 = __expf(sc2 - mnew), e3 = __expf(sc3 - mnew);
    float psum = e0 + e1 + e2 + e3;
#pragma unroll
    for (int m = 1; m <= 8; m <<= 1) psum += __shfl_xor(psum, m);
    const float alpha = __expf(m_run - mnew);
    l_run = l_run * alpha + psum;
    m_run = mnew;
    acc0 *= alpha; acc1 *= alpha; acc2 *= alpha; acc3 *= alpha;
    *(float4*)&pb[r][c4 * 4] = make_float4(e0, e1, e2, e3);
    // P @ V : acc[d = c4*4+cc] += sum_j p[r][j] * V[j][d]   (same-wave LDS round-trip)
    const float* vp = Vb + (size_t)j0t * DK + c4 * 4;
#pragma unroll 4
    for (int jj = 0; jj < 64; jj += 4) {
      const float4 pj = *(const float4*)&pb[r][jj];
      const float4 v0 = *(const float4*)(vp + (size_t)(jj + 0) * DK);
      const float4 v1 = *(const float4*)(vp + (size_t)(jj + 1) * DK);
      const float4 v2 = *(const float4*)(vp + (size_t)(jj + 2) * DK);
      const float4 v3 = *(const float4*)(vp + (size_t)(jj + 3) * DK);
      acc0 += pj.x * v0.x + pj.y * v1.x + pj.z * v2.x + pj.w * v3.x;
      acc1 += pj.x * v0.y + pj.y * v1.y + pj.z * v2.y + pj.w * v3.y;
      acc2 += pj.x * v0.z + pj.y * v1.z + pj.z * v2.z + pj.w * v3.z;
      acc3 += pj.x * v0.w + pj.y * v1.w + pj.z * v2.w + pj.w * v3.w;
    }
  }
  const float inv = 1.0f / l_run;
  const size_t o = ((size_t)b * SEQ + i) * DM + h * DK + c4 * 4;
  *(float4*)&ctx[o] = make_float4(acc0 * inv, acc1 * inv, acc2 * inv, acc3 * inv);
}

extern "C" void kernel_launch(void* const* d_in, const int* in_sizes, int n_in,
                              void* d_out, int out_size, void* d_ws, size_t ws_size,
                              hipStream_t stream) {
  (void)in_sizes; (void)n_in; (void)out_size; (void)ws_size;
  const float* X   = (const float*)d_in[0];
  const float* PE  = (const float*)d_in[1];
  const float* Wq  = (const float*)d_in[2];
  const float* Wk  = (const float*)d_in[3];
  const float* Wv  = (const float*)d_in[4];
  const float* Wo  = (const float*)d_in[5];
  const float* Wp  = (const float*)d_in[6];
  const float* ubv = (const float*)d_in[7];
  const float* vbv = (const float*)d_in[8];

  float* ws = (float*)d_ws;
  const size_t SZ = (size_t)4 * NH * SEQ * DK;  // 4 Mi floats
  float* Qw  = ws;            // [bh][s][d]
  float* Ktw = ws + SZ;       // [bh][d][s]
  float* Vw  = ws + 2 * SZ;   // [bh][s][d]
  float* Ptc = ws + 3 * SZ;   // 4 shifted copies of [h][d][s]  (= SZ floats total)
  float* ctx = ws + 4 * SZ;   // [b][s][dm]
  float* outp = (float*)d_out;

  dim3 blk(256);
  dim3 gA(8192 / 64, DM / 64);  // 128 x 8
  dim3 gP(SEQ / 64, DM / 64);   // 32 x 8
  hipLaunchKernelGGL(gemm512, gA, blk, 0, stream, X, Wq, Qw, 0);
  hipLaunchKernelGGL(gemm512, gA, blk, 0, stream, X, Wk, Ktw, 2);
  hipLaunchKernelGGL(gemm512, gA, blk, 0, stream, X, Wv, Vw, 0);
  hipLaunchKernelGGL(gemm512, gP, blk, 0, stream, PE, Wp, Ptc, 3);
  dim3 gAt(SEQ / 16, 4 * NH);   // 128 x 32
  hipLaunchKernelGGL(rel_attn, gAt, blk, 0, stream, Qw, Ktw, Vw, Ptc, ubv, vbv, ctx);
  hipLaunchKernelGGL(gemm512, gA, blk, 0, stream, ctx, Wo, outp, 1);
}

// Round 3
// 749.655 us; speedup vs baseline: 7.2278x; 7.2278x over previous
//
#include <hip/hip_runtime.h>
#include <hip/hip_bf16.h>
#include <math.h>

#define SEQ 2048
#define NH 8
#define DK 64
#define DM 512
#define RSCALE 0.125f
#define PPAD (SEQ + 128)   // P padded with 64 guard rows each side
#define POFF 64

typedef short s16x8 __attribute__((ext_vector_type(8)));
typedef float f32x4 __attribute__((ext_vector_type(4)));

static __device__ __forceinline__ unsigned short f2bf(float x) {
  __hip_bfloat16 h = __float2bfloat16(x);
  unsigned short u;
  __builtin_memcpy(&u, &h, 2);
  return u;
}

// ---------------- fp32 tiled GEMM: C = A(Mx512) @ W(512x512) ----------------
// mode 0 (Q): O1 = bf16(acc + u[h][d]), O2 = bf16(acc + v[h][d]), layout [bh][s][d]
// mode 1 (K): O1 = bf16(acc), layout [bh][s][d]
// mode 2 (V): O1 = bf16(acc), layout [bh][d][s]   (transposed)
// mode 3 (P): O1 = bf16(acc), layout [h][POFF+s][d] in padded buffer
// mode 4 (out): C = acc fp32, layout [m][n]
__global__ __launch_bounds__(256)
void gemm512(const float* __restrict__ A, const float* __restrict__ W,
             float* __restrict__ C, unsigned short* __restrict__ O1,
             unsigned short* __restrict__ O2, const float* __restrict__ ub,
             const float* __restrict__ vb, int mode) {
  __shared__ float As[16][68];
  __shared__ float Ws[16][68];
  const int tid = threadIdx.x;
  const int m0 = blockIdx.x * 64, n0 = blockIdx.y * 64;
  const int tx = tid & 15, ty = tid >> 4;
  const int lm = tid >> 2, lkq = (tid & 3) * 4;
  const int lk = tid >> 4, lnq = (tid & 15) * 4;
  float acc[4][4] = {};
  for (int k0 = 0; k0 < DM; k0 += 16) {
    const float4 a = *(const float4*)(A + (size_t)(m0 + lm) * DM + k0 + lkq);
    const float4 w = *(const float4*)(W + (size_t)(k0 + lk) * DM + n0 + lnq);
    As[lkq + 0][lm] = a.x; As[lkq + 1][lm] = a.y;
    As[lkq + 2][lm] = a.z; As[lkq + 3][lm] = a.w;
    *(float4*)&Ws[lk][lnq] = w;
    __syncthreads();
#pragma unroll
    for (int k = 0; k < 16; ++k) {
      const float4 b4 = *(const float4*)&Ws[k][tx * 4];
      const float a0 = As[k][ty * 4 + 0], a1 = As[k][ty * 4 + 1];
      const float a2 = As[k][ty * 4 + 2], a3 = As[k][ty * 4 + 3];
      acc[0][0] += a0 * b4.x; acc[0][1] += a0 * b4.y; acc[0][2] += a0 * b4.z; acc[0][3] += a0 * b4.w;
      acc[1][0] += a1 * b4.x; acc[1][1] += a1 * b4.y; acc[1][2] += a1 * b4.z; acc[1][3] += a1 * b4.w;
      acc[2][0] += a2 * b4.x; acc[2][1] += a2 * b4.y; acc[2][2] += a2 * b4.z; acc[2][3] += a2 * b4.w;
      acc[3][0] += a3 * b4.x; acc[3][1] += a3 * b4.y; acc[3][2] += a3 * b4.z; acc[3][3] += a3 * b4.w;
    }
    __syncthreads();
  }
#pragma unroll
  for (int im = 0; im < 4; ++im) {
    const int m = m0 + ty * 4 + im;
    const int b = m >> 11, s = m & (SEQ - 1);
#pragma unroll
    for (int in = 0; in < 4; ++in) {
      const int n = n0 + tx * 4 + in;
      const int h = n >> 6, d = n & 63;
      const float v = acc[im][in];
      if (mode == 0) {
        const size_t base = (((size_t)b * NH + h) * SEQ + s) * DK + d;
        O1[base] = f2bf(v + ub[h * DK + d]);
        O2[base] = f2bf(v + vb[h * DK + d]);
      } else if (mode == 1) {
        O1[(((size_t)b * NH + h) * SEQ + s) * DK + d] = f2bf(v);
      } else if (mode == 2) {
        O1[(((size_t)b * NH + h) * DK + d) * SEQ + s] = f2bf(v);
      } else if (mode == 3) {
        O1[((size_t)h * PPAD + POFF + s) * DK + d] = f2bf(v);
      } else {
        C[(size_t)m * DM + n] = v;
      }
    }
  }
}

// ---------------- MFMA flash relative attention (bf16 in, fp32 accum) --------
// Qu/Qv: [bh][s][d] bf16 (Q+u / Q+v), Kb: [bh][s][d], Vt: [bh][d][s],
// Pp: [h][PPAD][d] (row POFF+p = P[p]).  ctx out: [b][s][DM] fp32.
// Per block: 64 query rows (wave w owns 16); j-loop over S in steps of 32.
// pos scores via G[m][pp] = Qv_row . P[p0+pp] (width-48 GEMM) + diagonal extract.
__global__ __launch_bounds__(256)
void attn_mfma(const unsigned short* __restrict__ Qu, const unsigned short* __restrict__ Qv,
               const unsigned short* __restrict__ Kb, const unsigned short* __restrict__ Vt,
               const unsigned short* __restrict__ Pp, float* __restrict__ ctx) {
  const int bh = blockIdx.y;
  const int b = bh >> 3, h = bh & 7;
  const int w = threadIdx.x >> 6, lane = threadIdx.x & 63;
  const int c = lane & 15, q = lane >> 4;
  const int i0 = blockIdx.x * 64 + w * 16;

  __shared__ float G1s[4][16][48];
  __shared__ float G2s[4][16][48];
  __shared__ unsigned short Ps[4][16][32];

  const unsigned short* Qub = Qu + ((size_t)bh * SEQ + i0) * DK;
  const unsigned short* Qvb = Qv + ((size_t)bh * SEQ + i0) * DK;
  const unsigned short* Kbh = Kb + (size_t)bh * SEQ * DK;
  const unsigned short* Vbh = Vt + (size_t)bh * DK * SEQ;
  const unsigned short* Ph  = Pp + ((size_t)h * PPAD + POFF) * DK;

  // A-fragments (row m = lane&15, k = q*8 + jj)
  const s16x8 qu0 = *(const s16x8*)(Qub + (size_t)c * DK + q * 8);
  const s16x8 qu1 = *(const s16x8*)(Qub + (size_t)c * DK + 32 + q * 8);
  const s16x8 qv0 = *(const s16x8*)(Qvb + (size_t)c * DK + q * 8);
  const s16x8 qv1 = *(const s16x8*)(Qvb + (size_t)c * DK + 32 + q * 8);
  const s16x8 qw0 = *(const s16x8*)(Qvb + (size_t)(c + 1) * DK + q * 8);      // rows i0+1..i0+16
  const s16x8 qw1 = *(const s16x8*)(Qvb + (size_t)(c + 1) * DK + 32 + q * 8);

  f32x4 O[4];
  float mrun[4], lrun[4];
#pragma unroll
  for (int r = 0; r < 4; ++r) {
    O[r] = (f32x4){0.f, 0.f, 0.f, 0.f};
    mrun[r] = -INFINITY; lrun[r] = 0.f;
  }

  for (int j0 = 0; j0 < SEQ; j0 += 32) {
    // ---- content scores: two 16x16 C-tiles over j ----
    f32x4 S0 = {0.f, 0.f, 0.f, 0.f}, S1 = {0.f, 0.f, 0.f, 0.f};
    {
      const unsigned short* kp = Kbh + (size_t)(j0 + c) * DK + q * 8;
      const s16x8 k00 = *(const s16x8*)(kp);
      const s16x8 k01 = *(const s16x8*)(kp + 32);
      const s16x8 k10 = *(const s16x8*)(kp + 16 * DK);
      const s16x8 k11 = *(const s16x8*)(kp + 16 * DK + 32);
      S0 = __builtin_amdgcn_mfma_f32_16x16x32_bf16(qu0, k00, S0, 0, 0, 0);
      S0 = __builtin_amdgcn_mfma_f32_16x16x32_bf16(qu1, k01, S0, 0, 0, 0);
      S1 = __builtin_amdgcn_mfma_f32_16x16x32_bf16(qu0, k10, S1, 0, 0, 0);
      S1 = __builtin_amdgcn_mfma_f32_16x16x32_bf16(qu1, k11, S1, 0, 0, 0);
    }
    const int drel = j0 - i0;
    // ---- pos score GEMMs (width-48 diagonal band) ----
    if (drel <= 15) {  // region 1 present: p0 in [0, S-1]
      const unsigned short* pb = Ph + (size_t)(drel + SEQ - 16) * DK;
#pragma unroll
      for (int tt = 0; tt < 3; ++tt) {
        const unsigned short* pc = pb + (size_t)(tt * 16 + c) * DK + q * 8;
        const s16x8 p0 = *(const s16x8*)(pc);
        const s16x8 p1 = *(const s16x8*)(pc + 32);
        f32x4 G = {0.f, 0.f, 0.f, 0.f};
        G = __builtin_amdgcn_mfma_f32_16x16x32_bf16(qv0, p0, G, 0, 0, 0);
        G = __builtin_amdgcn_mfma_f32_16x16x32_bf16(qv1, p1, G, 0, 0, 0);
#pragma unroll
        for (int r = 0; r < 4; ++r) G1s[w][q * 4 + r][tt * 16 + c] = G[r];
      }
    }
    if (drel >= -29) {  // region 2 present: p2 in [-46, 2030] (guards cover)
      const unsigned short* pb = Ph + (ptrdiff_t)(drel - 17) * DK;
#pragma unroll
      for (int tt = 0; tt < 3; ++tt) {
        const unsigned short* pc = pb + (ptrdiff_t)(tt * 16 + c) * DK + q * 8;
        const s16x8 p0 = *(const s16x8*)(pc);
        const s16x8 p1 = *(const s16x8*)(pc + 32);
        f32x4 G = {0.f, 0.f, 0.f, 0.f};
        G = __builtin_amdgcn_mfma_f32_16x16x32_bf16(qw0, p0, G, 0, 0, 0);
        G = __builtin_amdgcn_mfma_f32_16x16x32_bf16(qw1, p1, G, 0, 0, 0);
#pragma unroll
        for (int r = 0; r < 4; ++r) G2s[w][q * 4 + r][tt * 16 + c] = G[r];
      }
    }
    // ---- assemble scores (C-layout: row m=q*4+r, col c, tiles t) ----
    float sc[2][4];
#pragma unroll
    for (int t = 0; t < 2; ++t) {
      const f32x4 Sv = t ? S1 : S0;
#pragma unroll
      for (int r = 0; r < 4; ++r) {
        const int m = q * 4 + r;
        const int dlt = drel + t * 16 + c - m;     // j - i
        const int pp = t * 16 + c - m + 15;        // in [0,46]
        const float* gsel = (dlt <= 0) ? &G1s[w][m][pp] : &G2s[w][m][pp];
        float pos = *gsel;
        if (dlt == 1) pos = 0.f;
        sc[t][r] = (Sv[r] + pos) * RSCALE;
      }
    }
    // ---- online softmax (rows live across 16 lanes of each quad) ----
    float alpha[4];
#pragma unroll
    for (int r = 0; r < 4; ++r) {
      float mx = fmaxf(sc[0][r], sc[1][r]);
#pragma unroll
      for (int d = 1; d <= 8; d <<= 1) mx = fmaxf(mx, __shfl_xor(mx, d));
      const float mnew = fmaxf(mrun[r], mx);
      const float e0 = __expf(sc[0][r] - mnew), e1 = __expf(sc[1][r] - mnew);
      float ps = e0 + e1;
#pragma unroll
      for (int d = 1; d <= 8; d <<= 1) ps += __shfl_xor(ps, d);
      alpha[r] = __expf(mrun[r] - mnew);
      lrun[r] = lrun[r] * alpha[r] + ps;
      mrun[r] = mnew;
      const int m = q * 4 + r;
      Ps[w][m][c] = f2bf(e0);
      Ps[w][m][16 + c] = f2bf(e1);
    }
#pragma unroll
    for (int dt = 0; dt < 4; ++dt)
#pragma unroll
      for (int r = 0; r < 4; ++r) O[dt][r] *= alpha[r];
    // ---- PV: prob back through LDS into A-layout, V^T as B-frags ----
    const s16x8 pa = *(const s16x8*)&Ps[w][c][q * 8];
#pragma unroll
    for (int dt = 0; dt < 4; ++dt) {
      const s16x8 vb = *(const s16x8*)(Vbh + (size_t)(dt * 16 + c) * SEQ + j0 + q * 8);
      O[dt] = __builtin_amdgcn_mfma_f32_16x16x32_bf16(pa, vb, O[dt], 0, 0, 0);
    }
  }
  // ---- epilogue: ctx[b][i][h*64+d] = O / l ----
  float inv[4];
#pragma unroll
  for (int r = 0; r < 4; ++r) inv[r] = 1.0f / lrun[r];
#pragma unroll
  for (int dt = 0; dt < 4; ++dt)
#pragma unroll
    for (int r = 0; r < 4; ++r) {
      const int i = i0 + q * 4 + r;
      ctx[((size_t)b * SEQ + i) * DM + h * DK + dt * 16 + c] = O[dt][r] * inv[r];
    }
}

extern "C" void kernel_launch(void* const* d_in, const int* in_sizes, int n_in,
                              void* d_out, int out_size, void* d_ws, size_t ws_size,
                              hipStream_t stream) {
  (void)in_sizes; (void)n_in; (void)out_size; (void)ws_size;
  const float* X   = (const float*)d_in[0];
  const float* PE  = (const float*)d_in[1];
  const float* Wq  = (const float*)d_in[2];
  const float* Wk  = (const float*)d_in[3];
  const float* Wv  = (const float*)d_in[4];
  const float* Wo  = (const float*)d_in[5];
  const float* Wp  = (const float*)d_in[6];
  const float* ubv = (const float*)d_in[7];
  const float* vbv = (const float*)d_in[8];

  const size_t NEL = (size_t)32 * SEQ * DK;  // 4 Mi elements per bf16 tensor
  unsigned short* qu = (unsigned short*)d_ws;
  unsigned short* qv = qu + NEL;   // overreads (<=16 rows) land in kb: safe
  unsigned short* kb = qv + NEL;
  unsigned short* vt = kb + NEL;
  unsigned short* pp = vt + NEL;                       // 8*PPAD*64 elements
  float* ctx = (float*)(pp + (size_t)NH * PPAD * DK);  // 4*2048*512 fp32
  float* outp = (float*)d_out;

  dim3 blk(256);
  dim3 gA(8192 / 64, DM / 64);  // 128 x 8
  dim3 gP(SEQ / 64, DM / 64);   // 32 x 8
  hipLaunchKernelGGL(gemm512, gA, blk, 0, stream, X, Wq, (float*)nullptr, qu, qv, ubv, vbv, 0);
  hipLaunchKernelGGL(gemm512, gA, blk, 0, stream, X, Wk, (float*)nullptr, kb, (unsigned short*)nullptr, (const float*)nullptr, (const float*)nullptr, 1);
  hipLaunchKernelGGL(gemm512, gA, blk, 0, stream, X, Wv, (float*)nullptr, vt, (unsigned short*)nullptr, (const float*)nullptr, (const float*)nullptr, 2);
  hipLaunchKernelGGL(gemm512, gP, blk, 0, stream, PE, Wp, (float*)nullptr, pp, (unsigned short*)nullptr, (const float*)nullptr, (const float*)nullptr, 3);
  dim3 gAt(SEQ / 64, 32);       // 32 x 32
  hipLaunchKernelGGL(attn_mfma, gAt, blk, 0, stream, qu, qv, kb, vt, pp, ctx);
  hipLaunchKernelGGL(gemm512, gA, blk, 0, stream, ctx, Wo, outp, (unsigned short*)nullptr, (unsigned short*)nullptr, (const float*)nullptr, (const float*)nullptr, 4);
}

// Round 4
// 653.720 us; speedup vs baseline: 8.2886x; 1.1468x over previous
//
#include <hip/hip_runtime.h>
#include <hip/hip_bf16.h>
#include <math.h>

#define SEQ 2048
#define NH 8
#define DK 64
#define DM 512
#define RSCALE 0.125f
#define PPAD (SEQ + 128)
#define POFF 64

typedef unsigned short ushortT;
typedef short s16x8 __attribute__((ext_vector_type(8)));
typedef float f32x4 __attribute__((ext_vector_type(4)));

static __device__ __forceinline__ ushortT f2bf(float x) {
  __hip_bfloat16 h = __float2bfloat16(x);
  ushortT u;
  __builtin_memcpy(&u, &h, 2);
  return u;
}

// ---- cast X (4M el) and PE (1M el) to bf16, vectorized x4 ----
__global__ __launch_bounds__(256)
void cast_in(const float* __restrict__ X, const float* __restrict__ PE,
             ushortT* __restrict__ Xb, ushortT* __restrict__ PEb) {
  const size_t i4 = (size_t)blockIdx.x * 256 + threadIdx.x;
  const size_t NX = (size_t)4 * SEQ * DM / 4;
  const float4 v = (i4 < NX) ? *(const float4*)(X + i4 * 4)
                             : *(const float4*)(PE + (i4 - NX) * 4);
  ushortT o[4] = {f2bf(v.x), f2bf(v.y), f2bf(v.z), f2bf(v.w)};
  ushortT* dst = (i4 < NX) ? (Xb + i4 * 4) : (PEb + (i4 - NX) * 4);
  *(ulonglong1*)dst = *(ulonglong1*)o;
}

// ---- transpose 5 weights 512x512 fp32 -> bf16 [n][k] ----
__global__ __launch_bounds__(256)
void transpose_w(const float* __restrict__ w0, const float* __restrict__ w1,
                 const float* __restrict__ w2, const float* __restrict__ w3,
                 const float* __restrict__ w4, ushortT* __restrict__ out) {
  __shared__ float ts[32][33];
  const int z = blockIdx.z;
  const float* w = (z == 0) ? w0 : (z == 1) ? w1 : (z == 2) ? w2 : (z == 3) ? w3 : w4;
  ushortT* o = out + (size_t)z * DM * DM;
  const int k0 = blockIdx.x * 32, n0 = blockIdx.y * 32;
  const int tx = threadIdx.x, ty = threadIdx.y;
#pragma unroll
  for (int i = 0; i < 4; ++i)
    ts[ty + i * 8][tx] = w[(size_t)(k0 + ty + i * 8) * DM + n0 + tx];
  __syncthreads();
#pragma unroll
  for (int i = 0; i < 4; ++i)
    o[(size_t)(n0 + ty + i * 8) * DM + k0 + tx] = f2bf(ts[tx][ty + i * 8]);
}

// ---- bf16 MFMA GEMM: C(Mx512) = A(Mx512) @ W(512x512), Wt = W^T bf16 ----
// block: 256 thr, tile 64(M) x 128(N); wave w covers n-sub w*32. No LDS.
// mode 0 (Q): qu=bf16(acc+u[gn]), qv=bf16(acc+v[gn]) at [bh][s][d]
// mode 1 (K): bf16 [bh][s][d];  mode 2 (V): bf16 [bh][d][s]
// mode 3 (P): bf16 [h][POFF+s][d];  mode 4: fp32 [m][n]
__global__ __launch_bounds__(256)
void gemm_mfma(const ushortT* __restrict__ A, const ushortT* __restrict__ Bt,
               const float* __restrict__ ubv, const float* __restrict__ vbv,
               ushortT* __restrict__ o1, ushortT* __restrict__ o2,
               float* __restrict__ of, int mode) {
  const int w = threadIdx.x >> 6, lane = threadIdx.x & 63;
  const int c = lane & 15, q = lane >> 4;
  const int m0 = blockIdx.x * 64;
  const int n0 = blockIdx.y * 128 + w * 32;

  const ushortT* Ab = A + (size_t)m0 * DM + q * 8;
  const ushortT* Bb = Bt + (size_t)n0 * DM + q * 8;

  f32x4 acc[4][2];
#pragma unroll
  for (int mt = 0; mt < 4; ++mt)
#pragma unroll
    for (int nt = 0; nt < 2; ++nt) acc[mt][nt] = (f32x4){0.f, 0.f, 0.f, 0.f};

  s16x8 a[4], bfr[2], an[4], bn[2];
#pragma unroll
  for (int mt = 0; mt < 4; ++mt) a[mt] = *(const s16x8*)(Ab + (size_t)(mt * 16 + c) * DM);
#pragma unroll
  for (int nt = 0; nt < 2; ++nt) bfr[nt] = *(const s16x8*)(Bb + (size_t)(nt * 16 + c) * DM);

  for (int k0 = 0; k0 < DM; k0 += 32) {
    if (k0 + 32 < DM) {
#pragma unroll
      for (int mt = 0; mt < 4; ++mt)
        an[mt] = *(const s16x8*)(Ab + (size_t)(mt * 16 + c) * DM + k0 + 32);
#pragma unroll
      for (int nt = 0; nt < 2; ++nt)
        bn[nt] = *(const s16x8*)(Bb + (size_t)(nt * 16 + c) * DM + k0 + 32);
    }
#pragma unroll
    for (int mt = 0; mt < 4; ++mt)
#pragma unroll
      for (int nt = 0; nt < 2; ++nt)
        acc[mt][nt] = __builtin_amdgcn_mfma_f32_16x16x32_bf16(a[mt], bfr[nt], acc[mt][nt], 0, 0, 0);
#pragma unroll
    for (int mt = 0; mt < 4; ++mt) a[mt] = an[mt];
#pragma unroll
    for (int nt = 0; nt < 2; ++nt) bfr[nt] = bn[nt];
  }

#pragma unroll
  for (int mt = 0; mt < 4; ++mt)
#pragma unroll
    for (int nt = 0; nt < 2; ++nt)
#pragma unroll
      for (int r = 0; r < 4; ++r) {
        const int gm = m0 + mt * 16 + q * 4 + r;
        const int gn = n0 + nt * 16 + c;
        const float v = acc[mt][nt][r];
        const int bb = gm >> 11, s = gm & (SEQ - 1);
        const int h = gn >> 6, d = gn & 63;
        if (mode == 0) {
          const size_t base = (((size_t)bb * NH + h) * SEQ + s) * DK + d;
          o1[base] = f2bf(v + ubv[gn]);
          o2[base] = f2bf(v + vbv[gn]);
        } else if (mode == 1) {
          o1[(((size_t)bb * NH + h) * SEQ + s) * DK + d] = f2bf(v);
        } else if (mode == 2) {
          o1[(((size_t)bb * NH + h) * DK + d) * SEQ + s] = f2bf(v);
        } else if (mode == 3) {
          o1[((size_t)h * PPAD + POFF + gm) * DK + d] = f2bf(v);
        } else {
          of[(size_t)gm * DM + gn] = v;
        }
      }
}

// ---- MFMA flash relative attention, no-max softmax, register G-bands ----
__global__ __launch_bounds__(256)
void attn_mfma(const ushortT* __restrict__ Qu, const ushortT* __restrict__ Qv,
               const ushortT* __restrict__ Kb, const ushortT* __restrict__ Vt,
               const ushortT* __restrict__ Pp, ushortT* __restrict__ ctxb) {
  const int bh = blockIdx.y, b = bh >> 3, h = bh & 7;
  const int w = threadIdx.x >> 6, lane = threadIdx.x & 63;
  const int c = lane & 15, q = lane >> 4;
  const int i0 = blockIdx.x * 64 + w * 16;

  __shared__ ushortT Ps[4][16][40];  // row stride 80B: 16B-aligned, ~2-way banks

  const ushortT* Qub = Qu + ((size_t)bh * SEQ + i0) * DK;
  const ushortT* Qvb = Qv + ((size_t)bh * SEQ + i0) * DK;
  const ushortT* Kbh = Kb + (size_t)bh * SEQ * DK;
  const ushortT* Vbh = Vt + (size_t)bh * DK * SEQ;
  const ushortT* Ph  = Pp + ((size_t)h * PPAD + POFF) * DK;

  const s16x8 qu0 = *(const s16x8*)(Qub + (size_t)c * DK + q * 8);
  const s16x8 qu1 = *(const s16x8*)(Qub + (size_t)c * DK + 32 + q * 8);
  const s16x8 qv0 = *(const s16x8*)(Qvb + (size_t)c * DK + q * 8);
  const s16x8 qv1 = *(const s16x8*)(Qvb + (size_t)c * DK + 32 + q * 8);
  const s16x8 qw0 = *(const s16x8*)(Qvb + (size_t)(c + 1) * DK + q * 8);
  const s16x8 qw1 = *(const s16x8*)(Qvb + (size_t)(c + 1) * DK + 32 + q * 8);

  // loop-invariant extraction constants: band elem G[m][pp] lives at reg r,
  // lane q*16+(pp&15); pp0 = c-m+15, tile = b0r + t'
  int sl[4], b0r[4];
#pragma unroll
  for (int r = 0; r < 4; ++r) {
    const int m = q * 4 + r;
    const int pp0 = c - m + 15;
    sl[r] = q * 16 + (pp0 & 15);
    b0r[r] = pp0 >> 4;
  }

  f32x4 O[4];
  float lsum[4];
#pragma unroll
  for (int r = 0; r < 4; ++r) { O[r] = (f32x4){0.f, 0.f, 0.f, 0.f}; lsum[r] = 0.f; }
  f32x4 g1[3], g2[3];

  for (int j0 = 0; j0 < SEQ; j0 += 32) {
    const int drel = j0 - i0;
    // content scores
    f32x4 S0 = {0.f, 0.f, 0.f, 0.f}, S1 = {0.f, 0.f, 0.f, 0.f};
    {
      const ushortT* kp = Kbh + (size_t)(j0 + c) * DK + q * 8;
      const s16x8 k00 = *(const s16x8*)(kp);
      const s16x8 k01 = *(const s16x8*)(kp + 32);
      const s16x8 k10 = *(const s16x8*)(kp + 16 * DK);
      const s16x8 k11 = *(const s16x8*)(kp + 16 * DK + 32);
      S0 = __builtin_amdgcn_mfma_f32_16x16x32_bf16(qu0, k00, S0, 0, 0, 0);
      S0 = __builtin_amdgcn_mfma_f32_16x16x32_bf16(qu1, k01, S0, 0, 0, 0);
      S1 = __builtin_amdgcn_mfma_f32_16x16x32_bf16(qu0, k10, S1, 0, 0, 0);
      S1 = __builtin_amdgcn_mfma_f32_16x16x32_bf16(qu1, k11, S1, 0, 0, 0);
    }
    const bool r1 = (drel <= 15), r2 = (drel >= -29);
    if (r1) {  // band rows base1+pp, base1 = drel+SEQ-16; rotate tile2->tile0
      const ushortT* pb = Ph + (ptrdiff_t)(drel + SEQ - 16) * DK;
      const int t0 = (j0 == 0) ? 0 : 1;
      if (j0 != 0) g1[0] = g1[2];
      for (int tt = t0; tt < 3; ++tt) {
        const ushortT* pc = pb + (ptrdiff_t)(tt * 16 + c) * DK + q * 8;
        f32x4 G = {0.f, 0.f, 0.f, 0.f};
        G = __builtin_amdgcn_mfma_f32_16x16x32_bf16(qv0, *(const s16x8*)pc, G, 0, 0, 0);
        G = __builtin_amdgcn_mfma_f32_16x16x32_bf16(qv1, *(const s16x8*)(pc + 32), G, 0, 0, 0);
        g1[tt] = G;
      }
    }
    if (r2) {  // band rows base2+pp, base2 = drel-17; A = Q rows +1
      const ushortT* pb = Ph + (ptrdiff_t)(drel - 17) * DK;
      const int t0 = (drel < 3) ? 0 : 1;
      if (drel >= 3) g2[0] = g2[2];
      for (int tt = t0; tt < 3; ++tt) {
        const ushortT* pc = pb + (ptrdiff_t)(tt * 16 + c) * DK + q * 8;
        f32x4 G = {0.f, 0.f, 0.f, 0.f};
        G = __builtin_amdgcn_mfma_f32_16x16x32_bf16(qw0, *(const s16x8*)pc, G, 0, 0, 0);
        G = __builtin_amdgcn_mfma_f32_16x16x32_bf16(qw1, *(const s16x8*)(pc + 32), G, 0, 0, 0);
        g2[tt] = G;
      }
    }
#pragma unroll
    for (int r = 0; r < 4; ++r) {
      const int m = q * 4 + r;
      float xA0 = 0.f, xA1 = 0.f, xB0 = 0.f, xB1 = 0.f;
      if (r1) {
        const float t0 = __shfl(g1[0][r], sl[r]);
        const float t1 = __shfl(g1[1][r], sl[r]);
        const float t2 = __shfl(g1[2][r], sl[r]);
        xA0 = b0r[r] ? t1 : t0;
        xA1 = b0r[r] ? t2 : t1;
      }
      if (r2) {
        const float t0 = __shfl(g2[0][r], sl[r]);
        const float t1 = __shfl(g2[1][r], sl[r]);
        const float t2 = __shfl(g2[2][r], sl[r]);
        xB0 = b0r[r] ? t1 : t0;
        xB1 = b0r[r] ? t2 : t1;
      }
      float pos0, pos1;
      if (!r2) { pos0 = xA0; pos1 = xA1; }
      else if (!r1) { pos0 = xB0; pos1 = xB1; }
      else {
        const int dlt0 = drel + c - m;
        pos0 = (dlt0 <= 0) ? xA0 : ((dlt0 == 1) ? 0.f : xB0);
        const int dlt1 = dlt0 + 16;
        pos1 = (dlt1 <= 0) ? xA1 : ((dlt1 == 1) ? 0.f : xB1);
      }
      const float e0 = __expf((S0[r] + pos0) * RSCALE);
      const float e1 = __expf((S1[r] + pos1) * RSCALE);
      lsum[r] += e0 + e1;
      Ps[w][m][c] = f2bf(e0);
      Ps[w][m][16 + c] = f2bf(e1);
    }
    // PV
    const s16x8 pa = *(const s16x8*)&Ps[w][c][q * 8];
#pragma unroll
    for (int dt = 0; dt < 4; ++dt) {
      const s16x8 vb = *(const s16x8*)(Vbh + (size_t)(dt * 16 + c) * SEQ + j0 + q * 8);
      O[dt] = __builtin_amdgcn_mfma_f32_16x16x32_bf16(pa, vb, O[dt], 0, 0, 0);
    }
  }
  float inv[4];
#pragma unroll
  for (int r = 0; r < 4; ++r) {
    float s = lsum[r];
#pragma unroll
    for (int d = 1; d <= 8; d <<= 1) s += __shfl_xor(s, d);
    inv[r] = 1.0f / s;
  }
#pragma unroll
  for (int dt = 0; dt < 4; ++dt)
#pragma unroll
    for (int r = 0; r < 4; ++r) {
      const int i = i0 + q * 4 + r;
      ctxb[((size_t)b * SEQ + i) * DM + h * DK + dt * 16 + c] = f2bf(O[dt][r] * inv[r]);
    }
}

extern "C" void kernel_launch(void* const* d_in, const int* in_sizes, int n_in,
                              void* d_out, int out_size, void* d_ws, size_t ws_size,
                              hipStream_t stream) {
  (void)in_sizes; (void)n_in; (void)out_size; (void)ws_size;
  const float* X   = (const float*)d_in[0];
  const float* PE  = (const float*)d_in[1];
  const float* Wq  = (const float*)d_in[2];
  const float* Wk  = (const float*)d_in[3];
  const float* Wv  = (const float*)d_in[4];
  const float* Wo  = (const float*)d_in[5];
  const float* Wp  = (const float*)d_in[6];
  const float* ubv = (const float*)d_in[7];
  const float* vbv = (const float*)d_in[8];

  const size_t NX = (size_t)4 * SEQ * DM;   // 4 Mi
  const size_t NP = (size_t)SEQ * DM;       // 1 Mi
  const size_t NW = (size_t)DM * DM;        // 256 Ki
  ushortT* Xb  = (ushortT*)d_ws;
  ushortT* PEb = Xb + NX;
  ushortT* Wt  = PEb + NP;                  // 5 transposed weights, bf16
  ushortT* qu  = Wt + 5 * NW;
  ushortT* qv  = qu + NX;
  ushortT* kb  = qv + NX;                   // qw overread from qv lands here: safe
  ushortT* vt  = kb + NX;
  ushortT* pp  = vt + NX;                   // NH*PPAD*DK
  ushortT* ctx = pp + (size_t)NH * PPAD * DK;
  float* outp = (float*)d_out;

  hipLaunchKernelGGL(cast_in, dim3((NX + NP) / 4 / 256), dim3(256), 0, stream, X, PE, Xb, PEb);
  hipLaunchKernelGGL(transpose_w, dim3(16, 16, 5), dim3(32, 8), 0, stream, Wq, Wk, Wv, Wp, Wo, Wt);
  dim3 blk(256);
  dim3 gA(8192 / 64, 4), gP(SEQ / 64, 4);
  hipLaunchKernelGGL(gemm_mfma, gA, blk, 0, stream, Xb, Wt + 0 * NW, ubv, vbv, qu, qv, (float*)nullptr, 0);
  hipLaunchKernelGGL(gemm_mfma, gA, blk, 0, stream, Xb, Wt + 1 * NW, ubv, vbv, kb, (ushortT*)nullptr, (float*)nullptr, 1);
  hipLaunchKernelGGL(gemm_mfma, gA, blk, 0, stream, Xb, Wt + 2 * NW, ubv, vbv, vt, (ushortT*)nullptr, (float*)nullptr, 2);
  hipLaunchKernelGGL(gemm_mfma, gP, blk, 0, stream, PEb, Wt + 3 * NW, ubv, vbv, pp, (ushortT*)nullptr, (float*)nullptr, 3);
  hipLaunchKernelGGL(attn_mfma, dim3(SEQ / 64, 32), blk, 0, stream, qu, qv, kb, vt, pp, ctx);
  hipLaunchKernelGGL(gemm_mfma, gA, blk, 0, stream, ctx, Wt + 4 * NW, ubv, vbv, (ushortT*)nullptr, (ushortT*)nullptr, outp, 4);
}

// Round 5
// 596.113 us; speedup vs baseline: 9.0895x; 1.0966x over previous
//
#include <hip/hip_runtime.h>
#include <hip/hip_bf16.h>
#include <math.h>

#define SEQ 2048
#define NH 8
#define DK 64
#define DM 512
#define RSCALE 0.125f
#define PPAD (SEQ + 128)
#define POFF 64

typedef unsigned short ushortT;
typedef short s16x8 __attribute__((ext_vector_type(8)));
typedef float f32x4 __attribute__((ext_vector_type(4)));

#define MFMA16 __builtin_amdgcn_mfma_f32_16x16x32_bf16

static __device__ __forceinline__ ushortT f2bf(float x) {
  __hip_bfloat16 h = __float2bfloat16(x);
  ushortT u;
  __builtin_memcpy(&u, &h, 2);
  return u;
}

// ---- cast X (4M el) and PE (1M el) to bf16, vectorized x4 ----
__global__ __launch_bounds__(256)
void cast_in(const float* __restrict__ X, const float* __restrict__ PE,
             ushortT* __restrict__ Xb, ushortT* __restrict__ PEb) {
  const size_t i4 = (size_t)blockIdx.x * 256 + threadIdx.x;
  const size_t NX = (size_t)4 * SEQ * DM / 4;
  const float4 v = (i4 < NX) ? *(const float4*)(X + i4 * 4)
                             : *(const float4*)(PE + (i4 - NX) * 4);
  ushortT o[4] = {f2bf(v.x), f2bf(v.y), f2bf(v.z), f2bf(v.w)};
  ushortT* dst = (i4 < NX) ? (Xb + i4 * 4) : (PEb + (i4 - NX) * 4);
  *(ulonglong1*)dst = *(ulonglong1*)o;
}

// ---- transpose 5 weights 512x512 fp32 -> bf16 [n][k] ----
__global__ __launch_bounds__(256)
void transpose_w(const float* __restrict__ w0, const float* __restrict__ w1,
                 const float* __restrict__ w2, const float* __restrict__ w3,
                 const float* __restrict__ w4, ushortT* __restrict__ out) {
  __shared__ float ts[32][33];
  const int z = blockIdx.z;
  const float* w = (z == 0) ? w0 : (z == 1) ? w1 : (z == 2) ? w2 : (z == 3) ? w3 : w4;
  ushortT* o = out + (size_t)z * DM * DM;
  const int k0 = blockIdx.x * 32, n0 = blockIdx.y * 32;
  const int tx = threadIdx.x, ty = threadIdx.y;
#pragma unroll
  for (int i = 0; i < 4; ++i)
    ts[ty + i * 8][tx] = w[(size_t)(k0 + ty + i * 8) * DM + n0 + tx];
  __syncthreads();
#pragma unroll
  for (int i = 0; i < 4; ++i)
    o[(size_t)(n0 + ty + i * 8) * DM + k0 + tx] = f2bf(ts[tx][ty + i * 8]);
}

// ---- bf16 MFMA GEMM: C(Mx512) = A(Mx512) @ W(512x512), Wt = W^T bf16 ----
// mode 0 (Q): qu=bf16((acc+u)*RSCALE), qv=bf16((acc+v)*RSCALE) at [bh][s][d]
// mode 1 (K): bf16 [bh][s][d];  mode 2 (V): bf16 [bh][d][s]
// mode 3 (P): bf16 [h][POFF+s][d];  mode 4: fp32 [m][n]
__global__ __launch_bounds__(256)
void gemm_mfma(const ushortT* __restrict__ A, const ushortT* __restrict__ Bt,
               const float* __restrict__ ubv, const float* __restrict__ vbv,
               ushortT* __restrict__ o1, ushortT* __restrict__ o2,
               float* __restrict__ of, int mode) {
  const int w = threadIdx.x >> 6, lane = threadIdx.x & 63;
  const int c = lane & 15, q = lane >> 4;
  const int m0 = blockIdx.x * 64;
  const int n0 = blockIdx.y * 128 + w * 32;

  const ushortT* Ab = A + (size_t)m0 * DM + q * 8;
  const ushortT* Bb = Bt + (size_t)n0 * DM + q * 8;

  f32x4 acc[4][2];
#pragma unroll
  for (int mt = 0; mt < 4; ++mt)
#pragma unroll
    for (int nt = 0; nt < 2; ++nt) acc[mt][nt] = (f32x4){0.f, 0.f, 0.f, 0.f};

  s16x8 a[4], bfr[2], an[4], bn[2];
#pragma unroll
  for (int mt = 0; mt < 4; ++mt) a[mt] = *(const s16x8*)(Ab + (size_t)(mt * 16 + c) * DM);
#pragma unroll
  for (int nt = 0; nt < 2; ++nt) bfr[nt] = *(const s16x8*)(Bb + (size_t)(nt * 16 + c) * DM);

  for (int k0 = 0; k0 < DM; k0 += 32) {
    if (k0 + 32 < DM) {
#pragma unroll
      for (int mt = 0; mt < 4; ++mt)
        an[mt] = *(const s16x8*)(Ab + (size_t)(mt * 16 + c) * DM + k0 + 32);
#pragma unroll
      for (int nt = 0; nt < 2; ++nt)
        bn[nt] = *(const s16x8*)(Bb + (size_t)(nt * 16 + c) * DM + k0 + 32);
    }
#pragma unroll
    for (int mt = 0; mt < 4; ++mt)
#pragma unroll
      for (int nt = 0; nt < 2; ++nt)
        acc[mt][nt] = MFMA16(a[mt], bfr[nt], acc[mt][nt], 0, 0, 0);
#pragma unroll
    for (int mt = 0; mt < 4; ++mt) a[mt] = an[mt];
#pragma unroll
    for (int nt = 0; nt < 2; ++nt) bfr[nt] = bn[nt];
  }

#pragma unroll
  for (int mt = 0; mt < 4; ++mt)
#pragma unroll
    for (int nt = 0; nt < 2; ++nt)
#pragma unroll
      for (int r = 0; r < 4; ++r) {
        const int gm = m0 + mt * 16 + q * 4 + r;
        const int gn = n0 + nt * 16 + c;
        const float v = acc[mt][nt][r];
        const int bb = gm >> 11, s = gm & (SEQ - 1);
        const int h = gn >> 6, d = gn & 63;
        if (mode == 0) {
          const size_t base = (((size_t)bb * NH + h) * SEQ + s) * DK + d;
          o1[base] = f2bf((v + ubv[gn]) * RSCALE);
          o2[base] = f2bf((v + vbv[gn]) * RSCALE);
        } else if (mode == 1) {
          o1[(((size_t)bb * NH + h) * SEQ + s) * DK + d] = f2bf(v);
        } else if (mode == 2) {
          o1[(((size_t)bb * NH + h) * DK + d) * SEQ + s] = f2bf(v);
        } else if (mode == 3) {
          o1[((size_t)h * PPAD + POFF + gm) * DK + d] = f2bf(v);
        } else {
          of[(size_t)gm * DM + gn] = v;
        }
      }
}

// ---- band GEMM helper: G = Qrow-block x P[tile*16 .. +15] ----
static __device__ __forceinline__ f32x4 band_gemm(const ushortT* pb, int tile,
                                                  int c, int q, s16x8 a0, s16x8 a1) {
  const ushortT* pc = pb + (ptrdiff_t)(tile * 16 + c) * DK + q * 8;
  f32x4 G = {0.f, 0.f, 0.f, 0.f};
  G = MFMA16(a0, *(const s16x8*)pc, G, 0, 0, 0);
  G = MFMA16(a1, *(const s16x8*)(pc + 32), G, 0, 0, 0);
  return G;
}

// ---- MFMA flash relative attention, skew-phased, j-split, atomic combine ----
__global__ __launch_bounds__(256)
void attn_mfma(const ushortT* __restrict__ Qu, const ushortT* __restrict__ Qv,
               const ushortT* __restrict__ Kb, const ushortT* __restrict__ Vt,
               const ushortT* __restrict__ Pp, float* __restrict__ Oacc,
               float* __restrict__ Lacc) {
  const int bh = blockIdx.y, jsp = blockIdx.z;
  const int w = threadIdx.x >> 6, lane = threadIdx.x & 63;
  const int c = lane & 15, q = lane >> 4;
  const int i0 = blockIdx.x * 64 + w * 16;

  __shared__ ushortT Ps[4][16][40];

  const ushortT* Qub = Qu + ((size_t)bh * SEQ + i0) * DK;
  const ushortT* Qvb = Qv + ((size_t)bh * SEQ + i0) * DK;
  const ushortT* Kbh = Kb + (size_t)bh * SEQ * DK;
  const ushortT* Vbh = Vt + (size_t)bh * DK * SEQ;
  const ushortT* Ph  = Pp + ((size_t)(bh & 7) * PPAD + POFF) * DK;

  const s16x8 qu0 = *(const s16x8*)(Qub + (size_t)c * DK + q * 8);
  const s16x8 qu1 = *(const s16x8*)(Qub + (size_t)c * DK + 32 + q * 8);
  const s16x8 qv0 = *(const s16x8*)(Qvb + (size_t)c * DK + q * 8);
  const s16x8 qv1 = *(const s16x8*)(Qvb + (size_t)c * DK + 32 + q * 8);
  const s16x8 qw0 = *(const s16x8*)(Qvb + (size_t)(c + 1) * DK + q * 8);
  const s16x8 qw1 = *(const s16x8*)(Qvb + (size_t)(c + 1) * DK + 32 + q * 8);

  // band extraction constants (loop-invariant): G[m][pp], pp0=c-m+15:
  // value lives at reg r, lane q*16+(pp0&15), tile b0r (+1 for the 2nd col-tile)
  int sl[4], b0r[4];
#pragma unroll
  for (int r = 0; r < 4; ++r) {
    const int m = q * 4 + r;
    const int pp0 = c - m + 15;
    sl[r] = q * 16 + (pp0 & 15);
    b0r[r] = pp0 >> 4;
  }

  f32x4 O[4];
  float lsum[4];
#pragma unroll
  for (int r = 0; r < 4; ++r) { O[r] = (f32x4){0.f, 0.f, 0.f, 0.f}; lsum[r] = 0.f; }
  f32x4 g1[3], g2[3];
  bool hv1 = false, hv2 = false;

  const int jstart = jsp * (SEQ / 2), jend = jstart + SEQ / 2;
  const int jt = i0 & ~31;                     // transition tile base
  const int jA1 = min(jt, jend);
  const int jB0 = max(jt, jstart), jB1 = min(jt + 64, jend);
  const int jC0 = max(jt + 64, jstart);

#define CONTENT_SCORES                                                        \
  f32x4 S0 = {0.f, 0.f, 0.f, 0.f}, S1 = {0.f, 0.f, 0.f, 0.f};                 \
  {                                                                           \
    const ushortT* kp = Kbh + (size_t)(j0 + c) * DK + q * 8;                  \
    const s16x8 k00 = *(const s16x8*)(kp);                                    \
    const s16x8 k01 = *(const s16x8*)(kp + 32);                               \
    const s16x8 k10 = *(const s16x8*)(kp + 16 * DK);                          \
    const s16x8 k11 = *(const s16x8*)(kp + 16 * DK + 32);                     \
    S0 = MFMA16(qu0, k00, S0, 0, 0, 0);                                       \
    S0 = MFMA16(qu1, k01, S0, 0, 0, 0);                                       \
    S1 = MFMA16(qu0, k10, S1, 0, 0, 0);                                       \
    S1 = MFMA16(qu1, k11, S1, 0, 0, 0);                                       \
  }

#define PV_STEP                                                               \
  {                                                                           \
    const s16x8 pa = *(const s16x8*)&Ps[w][c][q * 8];                         \
    _Pragma("unroll")                                                         \
    for (int dt = 0; dt < 4; ++dt) {                                          \
      const s16x8 vb = *(const s16x8*)(Vbh + (size_t)(dt * 16 + c) * SEQ + j0 + q * 8); \
      O[dt] = MFMA16(pa, vb, O[dt], 0, 0, 0);                                 \
    }                                                                         \
  }

  // ---------------- Phase A: region-1 only, branch-free ----------------
  for (int j0 = jstart; j0 < jA1; j0 += 32) {
    const int drel = j0 - i0;
    const ushortT* pb1 = Ph + (ptrdiff_t)(drel + SEQ - 16) * DK;
    if (hv1) g1[0] = g1[2]; else { g1[0] = band_gemm(pb1, 0, c, q, qv0, qv1); hv1 = true; }
    g1[1] = band_gemm(pb1, 1, c, q, qv0, qv1);
    g1[2] = band_gemm(pb1, 2, c, q, qv0, qv1);
    CONTENT_SCORES
#pragma unroll
    for (int r = 0; r < 4; ++r) {
      const float t0 = __shfl(g1[0][r], sl[r]);
      const float t1 = __shfl(g1[1][r], sl[r]);
      const float t2 = __shfl(g1[2][r], sl[r]);
      const float pos0 = b0r[r] ? t1 : t0;
      const float pos1 = b0r[r] ? t2 : t1;
      const float e0 = __expf(S0[r] + pos0);
      const float e1 = __expf(S1[r] + pos1);
      lsum[r] += e0 + e1;
      Ps[w][q * 4 + r][c] = f2bf(e0);
      Ps[w][q * 4 + r][16 + c] = f2bf(e1);
    }
    PV_STEP
  }
  // ---------------- Phase B: <=2 transition tiles, full select ----------------
  for (int j0 = jB0; j0 < jB1; j0 += 32) {
    const int drel = j0 - i0;
    const ushortT* pb1 = Ph + (ptrdiff_t)(drel + SEQ - 16) * DK;
    const ushortT* pb2 = Ph + (ptrdiff_t)(drel - 17) * DK;
    if (hv1) g1[0] = g1[2]; else { g1[0] = band_gemm(pb1, 0, c, q, qv0, qv1); hv1 = true; }
    g1[1] = band_gemm(pb1, 1, c, q, qv0, qv1);
    g1[2] = band_gemm(pb1, 2, c, q, qv0, qv1);
    if (hv2) g2[0] = g2[2]; else { g2[0] = band_gemm(pb2, 0, c, q, qw0, qw1); hv2 = true; }
    g2[1] = band_gemm(pb2, 1, c, q, qw0, qw1);
    g2[2] = band_gemm(pb2, 2, c, q, qw0, qw1);
    CONTENT_SCORES
#pragma unroll
    for (int r = 0; r < 4; ++r) {
      const int m = q * 4 + r;
      const float a0 = __shfl(g1[0][r], sl[r]);
      const float a1 = __shfl(g1[1][r], sl[r]);
      const float a2 = __shfl(g1[2][r], sl[r]);
      const float xA0 = b0r[r] ? a1 : a0;
      const float xA1 = b0r[r] ? a2 : a1;
      const float b0 = __shfl(g2[0][r], sl[r]);
      const float b1 = __shfl(g2[1][r], sl[r]);
      const float b2 = __shfl(g2[2][r], sl[r]);
      const float xB0 = b0r[r] ? b1 : b0;
      const float xB1 = b0r[r] ? b2 : b1;
      const int dlt0 = drel + c - m;
      const float pos0 = (dlt0 <= 0) ? xA0 : ((dlt0 == 1) ? 0.f : xB0);
      const int dlt1 = dlt0 + 16;
      const float pos1 = (dlt1 <= 0) ? xA1 : ((dlt1 == 1) ? 0.f : xB1);
      const float e0 = __expf(S0[r] + pos0);
      const float e1 = __expf(S1[r] + pos1);
      lsum[r] += e0 + e1;
      Ps[w][m][c] = f2bf(e0);
      Ps[w][m][16 + c] = f2bf(e1);
    }
    PV_STEP
  }
  // ---------------- Phase C: region-2 only, branch-free ----------------
  for (int j0 = jC0; j0 < jend; j0 += 32) {
    const int drel = j0 - i0;
    const ushortT* pb2 = Ph + (ptrdiff_t)(drel - 17) * DK;
    if (hv2) g2[0] = g2[2]; else { g2[0] = band_gemm(pb2, 0, c, q, qw0, qw1); hv2 = true; }
    g2[1] = band_gemm(pb2, 1, c, q, qw0, qw1);
    g2[2] = band_gemm(pb2, 2, c, q, qw0, qw1);
    CONTENT_SCORES
#pragma unroll
    for (int r = 0; r < 4; ++r) {
      const float t0 = __shfl(g2[0][r], sl[r]);
      const float t1 = __shfl(g2[1][r], sl[r]);
      const float t2 = __shfl(g2[2][r], sl[r]);
      const float pos0 = b0r[r] ? t1 : t0;
      const float pos1 = b0r[r] ? t2 : t1;
      const float e0 = __expf(S0[r] + pos0);
      const float e1 = __expf(S1[r] + pos1);
      lsum[r] += e0 + e1;
      Ps[w][q * 4 + r][c] = f2bf(e0);
      Ps[w][q * 4 + r][16 + c] = f2bf(e1);
    }
    PV_STEP
  }

  // ---- epilogue: atomic partial accumulation ----
  float* Ob = Oacc + (size_t)bh * SEQ * DK;
#pragma unroll
  for (int dt = 0; dt < 4; ++dt)
#pragma unroll
    for (int r = 0; r < 4; ++r)
      atomicAdd(&Ob[(size_t)(i0 + q * 4 + r) * DK + dt * 16 + c], O[dt][r]);
#pragma unroll
  for (int r = 0; r < 4; ++r) {
    float s = lsum[r];
#pragma unroll
    for (int d = 1; d <= 8; d <<= 1) s += __shfl_xor(s, d);
    if (c == 0) atomicAdd(&Lacc[bh * SEQ + i0 + q * 4 + r], s);
  }
}

// ---- combine: ctx = Oacc / Lacc, bf16 ----
__global__ __launch_bounds__(256)
void combine(const float* __restrict__ Oacc, const float* __restrict__ Lacc,
             ushortT* __restrict__ ctxb) {
  const int idx = blockIdx.x * 256 + threadIdx.x;
  const int bh = idx >> 15;
  const int i  = (idx >> 4) & (SEQ - 1);
  const int d4 = (idx & 15) * 4;
  const float4 o = *(const float4*)(Oacc + ((size_t)bh * SEQ + i) * DK + d4);
  const float inv = 1.0f / Lacc[bh * SEQ + i];
  const int b = bh >> 3, h = bh & 7;
  ushortT ov[4] = {f2bf(o.x * inv), f2bf(o.y * inv), f2bf(o.z * inv), f2bf(o.w * inv)};
  *(ulonglong1*)(ctxb + ((size_t)b * SEQ + i) * DM + h * DK + d4) = *(ulonglong1*)ov;
}

extern "C" void kernel_launch(void* const* d_in, const int* in_sizes, int n_in,
                              void* d_out, int out_size, void* d_ws, size_t ws_size,
                              hipStream_t stream) {
  (void)in_sizes; (void)n_in; (void)out_size; (void)ws_size;
  const float* X   = (const float*)d_in[0];
  const float* PE  = (const float*)d_in[1];
  const float* Wq  = (const float*)d_in[2];
  const float* Wk  = (const float*)d_in[3];
  const float* Wv  = (const float*)d_in[4];
  const float* Wo  = (const float*)d_in[5];
  const float* Wp  = (const float*)d_in[6];
  const float* ubv = (const float*)d_in[7];
  const float* vbv = (const float*)d_in[8];

  const size_t NX = (size_t)4 * SEQ * DM;   // 4 Mi
  const size_t NP = (size_t)SEQ * DM;       // 1 Mi
  const size_t NW = (size_t)DM * DM;        // 256 Ki
  ushortT* Xb  = (ushortT*)d_ws;
  ushortT* PEb = Xb + NX;
  ushortT* Wt  = PEb + NP;
  ushortT* qu  = Wt + 5 * NW;
  ushortT* qv  = qu + NX;
  ushortT* kb  = qv + NX;                   // qw overread from qv lands here: safe
  ushortT* vt  = kb + NX;
  ushortT* pp  = vt + NX;                   // NH*PPAD*DK
  ushortT* ctx = pp + (size_t)NH * PPAD * DK;
  float* Oacc  = (float*)(ctx + NX);        // 32*SEQ*DK fp32
  float* Lacc  = Oacc + (size_t)32 * SEQ * DK;  // 32*SEQ fp32
  float* outp = (float*)d_out;

  hipMemsetAsync(Oacc, 0, ((size_t)32 * SEQ * DK + 32 * SEQ) * sizeof(float), stream);
  hipLaunchKernelGGL(cast_in, dim3((NX + NP) / 4 / 256), dim3(256), 0, stream, X, PE, Xb, PEb);
  hipLaunchKernelGGL(transpose_w, dim3(16, 16, 5), dim3(32, 8), 0, stream, Wq, Wk, Wv, Wp, Wo, Wt);
  dim3 blk(256);
  dim3 gA(8192 / 64, 4), gP(SEQ / 64, 4);
  hipLaunchKernelGGL(gemm_mfma, gA, blk, 0, stream, Xb, Wt + 0 * NW, ubv, vbv, qu, qv, (float*)nullptr, 0);
  hipLaunchKernelGGL(gemm_mfma, gA, blk, 0, stream, Xb, Wt + 1 * NW, ubv, vbv, kb, (ushortT*)nullptr, (float*)nullptr, 1);
  hipLaunchKernelGGL(gemm_mfma, gA, blk, 0, stream, Xb, Wt + 2 * NW, ubv, vbv, vt, (ushortT*)nullptr, (float*)nullptr, 2);
  hipLaunchKernelGGL(gemm_mfma, gP, blk, 0, stream, PEb, Wt + 3 * NW, ubv, vbv, pp, (ushortT*)nullptr, (float*)nullptr, 3);
  hipLaunchKernelGGL(attn_mfma, dim3(SEQ / 64, 32, 2), blk, 0, stream, qu, qv, kb, vt, pp, Oacc, Lacc);
  hipLaunchKernelGGL(combine, dim3(32 * SEQ * 16 / 256), blk, 0, stream, Oacc, Lacc, ctx);
  hipLaunchKernelGGL(gemm_mfma, gA, blk, 0, stream, ctx, Wt + 4 * NW, ubv, vbv, (ushortT*)nullptr, (ushortT*)nullptr, outp, 4);
}

// Round 6
// 563.101 us; speedup vs baseline: 9.6224x; 1.0586x over previous
//
#include <hip/hip_runtime.h>
#include <hip/hip_bf16.h>
#include <math.h>

#define SEQ 2048
#define NH 8
#define DK 64
#define DM 512
#define RSCALE 0.125f
#define PPAD (SEQ + 128)
#define POFF 64

typedef unsigned short ushortT;
typedef short s16x8 __attribute__((ext_vector_type(8)));
typedef float f32x4 __attribute__((ext_vector_type(4)));

#define MFMA16 __builtin_amdgcn_mfma_f32_16x16x32_bf16

static __device__ __forceinline__ ushortT f2bf(float x) {
  __hip_bfloat16 h = __float2bfloat16(x);
  ushortT u;
  __builtin_memcpy(&u, &h, 2);
  return u;
}

// ---- cast X (4M el) and PE (1M el) to bf16, vectorized x4 ----
__global__ __launch_bounds__(256)
void cast_in(const float* __restrict__ X, const float* __restrict__ PE,
             ushortT* __restrict__ Xb, ushortT* __restrict__ PEb) {
  const size_t i4 = (size_t)blockIdx.x * 256 + threadIdx.x;
  const size_t NX = (size_t)4 * SEQ * DM / 4;
  const float4 v = (i4 < NX) ? *(const float4*)(X + i4 * 4)
                             : *(const float4*)(PE + (i4 - NX) * 4);
  ushortT o[4] = {f2bf(v.x), f2bf(v.y), f2bf(v.z), f2bf(v.w)};
  ushortT* dst = (i4 < NX) ? (Xb + i4 * 4) : (PEb + (i4 - NX) * 4);
  *(ulonglong1*)dst = *(ulonglong1*)o;
}

// ---- transpose 5 weights 512x512 fp32 -> bf16 [n][k] ----
__global__ __launch_bounds__(256)
void transpose_w(const float* __restrict__ w0, const float* __restrict__ w1,
                 const float* __restrict__ w2, const float* __restrict__ w3,
                 const float* __restrict__ w4, ushortT* __restrict__ out) {
  __shared__ float ts[32][33];
  const int z = blockIdx.z;
  const float* w = (z == 0) ? w0 : (z == 1) ? w1 : (z == 2) ? w2 : (z == 3) ? w3 : w4;
  ushortT* o = out + (size_t)z * DM * DM;
  const int k0 = blockIdx.x * 32, n0 = blockIdx.y * 32;
  const int tx = threadIdx.x, ty = threadIdx.y;
#pragma unroll
  for (int i = 0; i < 4; ++i)
    ts[ty + i * 8][tx] = w[(size_t)(k0 + ty + i * 8) * DM + n0 + tx];
  __syncthreads();
#pragma unroll
  for (int i = 0; i < 4; ++i)
    o[(size_t)(n0 + ty + i * 8) * DM + k0 + tx] = f2bf(ts[tx][ty + i * 8]);
}

// ---- bf16 MFMA GEMM: C(Mx512) = A(Mx512) @ W(512x512), Wt = W^T bf16 ----
// mode 0 (Q): qu=bf16((acc+u)*RSCALE), qv=bf16((acc+v)*RSCALE) at [bh][s][d]
// mode 1 (K): bf16 [bh][s][d];  mode 2 (V): bf16 [bh][d][s]
// mode 3 (P): bf16 [h][POFF+s][d];  mode 4: fp32 [m][n]
__global__ __launch_bounds__(256)
void gemm_mfma(const ushortT* __restrict__ A, const ushortT* __restrict__ Bt,
               const float* __restrict__ ubv, const float* __restrict__ vbv,
               ushortT* __restrict__ o1, ushortT* __restrict__ o2,
               float* __restrict__ of, int mode) {
  const int w = threadIdx.x >> 6, lane = threadIdx.x & 63;
  const int c = lane & 15, q = lane >> 4;
  const int m0 = blockIdx.x * 64;
  const int n0 = blockIdx.y * 128 + w * 32;

  const ushortT* Ab = A + (size_t)m0 * DM + q * 8;
  const ushortT* Bb = Bt + (size_t)n0 * DM + q * 8;

  f32x4 acc[4][2];
#pragma unroll
  for (int mt = 0; mt < 4; ++mt)
#pragma unroll
    for (int nt = 0; nt < 2; ++nt) acc[mt][nt] = (f32x4){0.f, 0.f, 0.f, 0.f};

  s16x8 a[4], bfr[2], an[4], bn[2];
#pragma unroll
  for (int mt = 0; mt < 4; ++mt) a[mt] = *(const s16x8*)(Ab + (size_t)(mt * 16 + c) * DM);
#pragma unroll
  for (int nt = 0; nt < 2; ++nt) bfr[nt] = *(const s16x8*)(Bb + (size_t)(nt * 16 + c) * DM);

  for (int k0 = 0; k0 < DM; k0 += 32) {
    if (k0 + 32 < DM) {
#pragma unroll
      for (int mt = 0; mt < 4; ++mt)
        an[mt] = *(const s16x8*)(Ab + (size_t)(mt * 16 + c) * DM + k0 + 32);
#pragma unroll
      for (int nt = 0; nt < 2; ++nt)
        bn[nt] = *(const s16x8*)(Bb + (size_t)(nt * 16 + c) * DM + k0 + 32);
    }
#pragma unroll
    for (int mt = 0; mt < 4; ++mt)
#pragma unroll
      for (int nt = 0; nt < 2; ++nt)
        acc[mt][nt] = MFMA16(a[mt], bfr[nt], acc[mt][nt], 0, 0, 0);
#pragma unroll
    for (int mt = 0; mt < 4; ++mt) a[mt] = an[mt];
#pragma unroll
    for (int nt = 0; nt < 2; ++nt) bfr[nt] = bn[nt];
  }

#pragma unroll
  for (int mt = 0; mt < 4; ++mt)
#pragma unroll
    for (int nt = 0; nt < 2; ++nt)
#pragma unroll
      for (int r = 0; r < 4; ++r) {
        const int gm = m0 + mt * 16 + q * 4 + r;
        const int gn = n0 + nt * 16 + c;
        const float v = acc[mt][nt][r];
        const int bb = gm >> 11, s = gm & (SEQ - 1);
        const int h = gn >> 6, d = gn & 63;
        if (mode == 0) {
          const size_t base = (((size_t)bb * NH + h) * SEQ + s) * DK + d;
          o1[base] = f2bf((v + ubv[gn]) * RSCALE);
          o2[base] = f2bf((v + vbv[gn]) * RSCALE);
        } else if (mode == 1) {
          o1[(((size_t)bb * NH + h) * SEQ + s) * DK + d] = f2bf(v);
        } else if (mode == 2) {
          o1[(((size_t)bb * NH + h) * DK + d) * SEQ + s] = f2bf(v);
        } else if (mode == 3) {
          o1[((size_t)h * PPAD + POFF + gm) * DK + d] = f2bf(v);
        } else {
          of[(size_t)gm * DM + gn] = v;
        }
      }
}

// ---- band GEMM helper: G = Qrow-block x P[tile*16 .. +15] ----
static __device__ __forceinline__ f32x4 band_gemm(const ushortT* pb, int tile,
                                                  int c, int q, s16x8 a0, s16x8 a1) {
  const ushortT* pc = pb + (ptrdiff_t)(tile * 16 + c) * DK + q * 8;
  f32x4 G = {0.f, 0.f, 0.f, 0.f};
  G = MFMA16(a0, *(const s16x8*)pc, G, 0, 0, 0);
  G = MFMA16(a1, *(const s16x8*)(pc + 32), G, 0, 0, 0);
  return G;
}

// ---- MFMA flash relative attention; XCD-swizzled grid, K/V reg pipeline ----
__global__ __launch_bounds__(256)
void attn_mfma(const ushortT* __restrict__ Qu, const ushortT* __restrict__ Qv,
               const ushortT* __restrict__ Kb, const ushortT* __restrict__ Vt,
               const ushortT* __restrict__ Pp, ushortT* __restrict__ ctxb) {
  // swizzle: XCD x (dispatch round-robin over n%8) serves h=x, 4 batches ->
  // per-XCD L2 set = K+V (2MB) + one head's P (1.1MB)
  const int n = blockIdx.x;
  const int xcd = n & 7, idx = n >> 3;
  const int bgrp = idx >> 5, iblk = idx & 31;
  const int bh = bgrp * 8 + xcd;
  const int b = bgrp, h = xcd;
  const int w = threadIdx.x >> 6, lane = threadIdx.x & 63;
  const int c = lane & 15, q = lane >> 4;
  const int i0 = iblk * 64 + w * 16;

  __shared__ ushortT Ps[4][16][40];

  const ushortT* Qub = Qu + ((size_t)bh * SEQ + i0) * DK;
  const ushortT* Qvb = Qv + ((size_t)bh * SEQ + i0) * DK;
  const ushortT* Kbh = Kb + (size_t)bh * SEQ * DK;
  const ushortT* Vbh = Vt + (size_t)bh * DK * SEQ;
  const ushortT* Ph  = Pp + ((size_t)h * PPAD + POFF) * DK;

  const s16x8 qu0 = *(const s16x8*)(Qub + (size_t)c * DK + q * 8);
  const s16x8 qu1 = *(const s16x8*)(Qub + (size_t)c * DK + 32 + q * 8);
  const s16x8 qv0 = *(const s16x8*)(Qvb + (size_t)c * DK + q * 8);
  const s16x8 qv1 = *(const s16x8*)(Qvb + (size_t)c * DK + 32 + q * 8);
  const s16x8 qw0 = *(const s16x8*)(Qvb + (size_t)(c + 1) * DK + q * 8);
  const s16x8 qw1 = *(const s16x8*)(Qvb + (size_t)(c + 1) * DK + 32 + q * 8);

  int sl[4], b0r[4];
#pragma unroll
  for (int r = 0; r < 4; ++r) {
    const int m = q * 4 + r;
    const int pp0 = c - m + 15;
    sl[r] = q * 16 + (pp0 & 15);
    b0r[r] = pp0 >> 4;
  }

  f32x4 O[4];
  float lsum[4];
#pragma unroll
  for (int r = 0; r < 4; ++r) { O[r] = (f32x4){0.f, 0.f, 0.f, 0.f}; lsum[r] = 0.f; }
  f32x4 g1[3], g2[3];
  bool hv1 = false, hv2 = false;

  const int jt = i0 & ~31;
  const int jA1 = jt;
  const int jB1 = min(jt + 64, SEQ);

  s16x8 kc[4], vc[4], kn[4], vn[4];

#define LOADK(dst, jj)                                                        \
  {                                                                           \
    const ushortT* kp = Kbh + (size_t)((jj) + c) * DK + q * 8;                \
    dst[0] = *(const s16x8*)(kp);                                             \
    dst[1] = *(const s16x8*)(kp + 32);                                        \
    dst[2] = *(const s16x8*)(kp + 16 * DK);                                   \
    dst[3] = *(const s16x8*)(kp + 16 * DK + 32);                              \
  }
#define LOADV(dst, jj)                                                        \
  {                                                                           \
    _Pragma("unroll")                                                         \
    for (int dt = 0; dt < 4; ++dt)                                            \
      dst[dt] = *(const s16x8*)(Vbh + (size_t)(dt * 16 + c) * SEQ + (jj) + q * 8); \
  }

#define CONTENT_FR                                                            \
  f32x4 S0 = {0.f, 0.f, 0.f, 0.f}, S1 = {0.f, 0.f, 0.f, 0.f};                 \
  S0 = MFMA16(qu0, kc[0], S0, 0, 0, 0);                                       \
  S0 = MFMA16(qu1, kc[1], S0, 0, 0, 0);                                       \
  S1 = MFMA16(qu0, kc[2], S1, 0, 0, 0);                                       \
  S1 = MFMA16(qu1, kc[3], S1, 0, 0, 0);

#define PV_FR                                                                 \
  {                                                                           \
    const s16x8 pa = *(const s16x8*)&Ps[w][c][q * 8];                         \
    _Pragma("unroll")                                                         \
    for (int dt = 0; dt < 4; ++dt) O[dt] = MFMA16(pa, vc[dt], O[dt], 0, 0, 0);\
  }

#define ADVANCE                                                               \
  _Pragma("unroll")                                                           \
  for (int ii = 0; ii < 4; ++ii) { kc[ii] = kn[ii]; vc[ii] = vn[ii]; }

  // ---------------- Phase A: region-1 only, branch-free ----------------
  if (0 < jA1) {
    LOADK(kc, 0); LOADV(vc, 0);
    for (int j0 = 0; j0 < jA1; j0 += 32) {
      const bool hn = (j0 + 32) < jA1;
      if (hn) { LOADK(kn, j0 + 32); LOADV(vn, j0 + 32); }
      const int drel = j0 - i0;
      const ushortT* pb1 = Ph + (ptrdiff_t)(drel + SEQ - 16) * DK;
      if (hv1) g1[0] = g1[2]; else { g1[0] = band_gemm(pb1, 0, c, q, qv0, qv1); hv1 = true; }
      g1[1] = band_gemm(pb1, 1, c, q, qv0, qv1);
      g1[2] = band_gemm(pb1, 2, c, q, qv0, qv1);
      CONTENT_FR
#pragma unroll
      for (int r = 0; r < 4; ++r) {
        const float t0 = __shfl(g1[0][r], sl[r]);
        const float t1 = __shfl(g1[1][r], sl[r]);
        const float t2 = __shfl(g1[2][r], sl[r]);
        const float pos0 = b0r[r] ? t1 : t0;
        const float pos1 = b0r[r] ? t2 : t1;
        const float e0 = __expf(S0[r] + pos0);
        const float e1 = __expf(S1[r] + pos1);
        lsum[r] += e0 + e1;
        Ps[w][q * 4 + r][c] = f2bf(e0);
        Ps[w][q * 4 + r][16 + c] = f2bf(e1);
      }
      PV_FR
      if (hn) { ADVANCE }
    }
  }
  // ---------------- Phase B: <=2 transition tiles, full select ----------------
  for (int j0 = jt; j0 < jB1; j0 += 32) {
    LOADK(kc, j0); LOADV(vc, j0);
    const int drel = j0 - i0;
    const ushortT* pb1 = Ph + (ptrdiff_t)(drel + SEQ - 16) * DK;
    const ushortT* pb2 = Ph + (ptrdiff_t)(drel - 17) * DK;
    if (hv1) g1[0] = g1[2]; else { g1[0] = band_gemm(pb1, 0, c, q, qv0, qv1); hv1 = true; }
    g1[1] = band_gemm(pb1, 1, c, q, qv0, qv1);
    g1[2] = band_gemm(pb1, 2, c, q, qv0, qv1);
    if (hv2) g2[0] = g2[2]; else { g2[0] = band_gemm(pb2, 0, c, q, qw0, qw1); hv2 = true; }
    g2[1] = band_gemm(pb2, 1, c, q, qw0, qw1);
    g2[2] = band_gemm(pb2, 2, c, q, qw0, qw1);
    CONTENT_FR
#pragma unroll
    for (int r = 0; r < 4; ++r) {
      const int m = q * 4 + r;
      const float a0 = __shfl(g1[0][r], sl[r]);
      const float a1 = __shfl(g1[1][r], sl[r]);
      const float a2 = __shfl(g1[2][r], sl[r]);
      const float xA0 = b0r[r] ? a1 : a0;
      const float xA1 = b0r[r] ? a2 : a1;
      const float b0 = __shfl(g2[0][r], sl[r]);
      const float b1 = __shfl(g2[1][r], sl[r]);
      const float b2 = __shfl(g2[2][r], sl[r]);
      const float xB0 = b0r[r] ? b1 : b0;
      const float xB1 = b0r[r] ? b2 : b1;
      const int dlt0 = drel + c - m;
      const float pos0 = (dlt0 <= 0) ? xA0 : ((dlt0 == 1) ? 0.f : xB0);
      const int dlt1 = dlt0 + 16;
      const float pos1 = (dlt1 <= 0) ? xA1 : ((dlt1 == 1) ? 0.f : xB1);
      const float e0 = __expf(S0[r] + pos0);
      const float e1 = __expf(S1[r] + pos1);
      lsum[r] += e0 + e1;
      Ps[w][m][c] = f2bf(e0);
      Ps[w][m][16 + c] = f2bf(e1);
    }
    PV_FR
  }
  // ---------------- Phase C: region-2 only, branch-free ----------------
  if (jB1 < SEQ) {
    LOADK(kc, jB1); LOADV(vc, jB1);
    for (int j0 = jB1; j0 < SEQ; j0 += 32) {
      const bool hn = (j0 + 32) < SEQ;
      if (hn) { LOADK(kn, j0 + 32); LOADV(vn, j0 + 32); }
      const int drel = j0 - i0;
      const ushortT* pb2 = Ph + (ptrdiff_t)(drel - 17) * DK;
      if (hv2) g2[0] = g2[2]; else { g2[0] = band_gemm(pb2, 0, c, q, qw0, qw1); hv2 = true; }
      g2[1] = band_gemm(pb2, 1, c, q, qw0, qw1);
      g2[2] = band_gemm(pb2, 2, c, q, qw0, qw1);
      CONTENT_FR
#pragma unroll
      for (int r = 0; r < 4; ++r) {
        const float t0 = __shfl(g2[0][r], sl[r]);
        const float t1 = __shfl(g2[1][r], sl[r]);
        const float t2 = __shfl(g2[2][r], sl[r]);
        const float pos0 = b0r[r] ? t1 : t0;
        const float pos1 = b0r[r] ? t2 : t1;
        const float e0 = __expf(S0[r] + pos0);
        const float e1 = __expf(S1[r] + pos1);
        lsum[r] += e0 + e1;
        Ps[w][q * 4 + r][c] = f2bf(e0);
        Ps[w][q * 4 + r][16 + c] = f2bf(e1);
      }
      PV_FR
      if (hn) { ADVANCE }
    }
  }

  // ---- epilogue: divide by row sum, write bf16 ctx ----
  float inv[4];
#pragma unroll
  for (int r = 0; r < 4; ++r) {
    float s = lsum[r];
#pragma unroll
    for (int d = 1; d <= 8; d <<= 1) s += __shfl_xor(s, d);
    inv[r] = 1.0f / s;
  }
#pragma unroll
  for (int dt = 0; dt < 4; ++dt)
#pragma unroll
    for (int r = 0; r < 4; ++r) {
      const int i = i0 + q * 4 + r;
      ctxb[((size_t)b * SEQ + i) * DM + h * DK + dt * 16 + c] = f2bf(O[dt][r] * inv[r]);
    }
}

extern "C" void kernel_launch(void* const* d_in, const int* in_sizes, int n_in,
                              void* d_out, int out_size, void* d_ws, size_t ws_size,
                              hipStream_t stream) {
  (void)in_sizes; (void)n_in; (void)out_size; (void)ws_size;
  const float* X   = (const float*)d_in[0];
  const float* PE  = (const float*)d_in[1];
  const float* Wq  = (const float*)d_in[2];
  const float* Wk  = (const float*)d_in[3];
  const float* Wv  = (const float*)d_in[4];
  const float* Wo  = (const float*)d_in[5];
  const float* Wp  = (const float*)d_in[6];
  const float* ubv = (const float*)d_in[7];
  const float* vbv = (const float*)d_in[8];

  const size_t NX = (size_t)4 * SEQ * DM;   // 4 Mi
  const size_t NP = (size_t)SEQ * DM;       // 1 Mi
  const size_t NW = (size_t)DM * DM;        // 256 Ki
  ushortT* Xb  = (ushortT*)d_ws;
  ushortT* PEb = Xb + NX;
  ushortT* Wt  = PEb + NP;
  ushortT* qu  = Wt + 5 * NW;
  ushortT* qv  = qu + NX;
  ushortT* kb  = qv + NX;                   // qw overread from qv lands here: safe
  ushortT* vt  = kb + NX;
  ushortT* pp  = vt + NX;                   // NH*PPAD*DK
  ushortT* ctx = pp + (size_t)NH * PPAD * DK;
  float* outp = (float*)d_out;

  hipLaunchKernelGGL(cast_in, dim3((NX + NP) / 4 / 256), dim3(256), 0, stream, X, PE, Xb, PEb);
  hipLaunchKernelGGL(transpose_w, dim3(16, 16, 5), dim3(32, 8), 0, stream, Wq, Wk, Wv, Wp, Wo, Wt);
  dim3 blk(256);
  dim3 gA(8192 / 64, 4), gP(SEQ / 64, 4);
  hipLaunchKernelGGL(gemm_mfma, gA, blk, 0, stream, Xb, Wt + 0 * NW, ubv, vbv, qu, qv, (float*)nullptr, 0);
  hipLaunchKernelGGL(gemm_mfma, gA, blk, 0, stream, Xb, Wt + 1 * NW, ubv, vbv, kb, (ushortT*)nullptr, (float*)nullptr, 1);
  hipLaunchKernelGGL(gemm_mfma, gA, blk, 0, stream, Xb, Wt + 2 * NW, ubv, vbv, vt, (ushortT*)nullptr, (float*)nullptr, 2);
  hipLaunchKernelGGL(gemm_mfma, gP, blk, 0, stream, PEb, Wt + 3 * NW, ubv, vbv, pp, (ushortT*)nullptr, (float*)nullptr, 3);
  hipLaunchKernelGGL(attn_mfma, dim3(1024), blk, 0, stream, qu, qv, kb, vt, pp, ctx);
  hipLaunchKernelGGL(gemm_mfma, gA, blk, 0, stream, ctx, Wt + 4 * NW, ubv, vbv, (ushortT*)nullptr, (ushortT*)nullptr, outp, 4);
}